// Round 15
// baseline (59.381 us; speedup 1.0000x reference)
//
#include <hip/hip_runtime.h>

// Neo-Hookean constants (match reference)
#define MU_C   3846.1538461538462f   // E/(2(1+nu))
#define LM_C   5769.2307692307695f   // E*nu/((1+nu)(1-2nu))
#define LOGC   (MU_C + 0.5f * LM_C)  // combined log coefficient
#define EPS_C  1e-10f

typedef float nf4 __attribute__((ext_vector_type(4)));
typedef int   ni4 __attribute__((ext_vector_type(4)));

// v15: time-decoupled pipeline. Persistent-chunk blocks; per iteration:
//   (1) issue nt stream loads for tile m+1 -> regs   (HBM latency hides under compute)
//   (2) compute tile m from LDS + prefetched uu regs
//   (3) barrier; ds_write staged regs -> alt buffer; barrier
//   (4) read el(m+1) from LDS, issue ut gathers -> alternate uu regs
// SLAB=52 padding (bank stride 20 -> 2-way, free). No sched_barrier (v9 spill
// trigger), no launch_bounds cap (v7 spill trigger), named A/B reg sets.
#define ELB  64
#define SLAB 52
#define NBLK 1024

__global__ __launch_bounds__(256) void nh_transpose_u_pad(
    const float* __restrict__ u, float4* __restrict__ ut, int n_nodes)
{
    const int i = blockIdx.x * 256 + threadIdx.x;
    if (i >= n_nodes) return;
    float4* q = ut + (size_t)i * 4;
    #pragma unroll
    for (int b = 0; b < 4; ++b) {
        const float* p = u + ((size_t)b * n_nodes + i) * 3;
        q[b] = make_float4(p[0], p[1], p[2], 0.f);
    }
}

__device__ __forceinline__ float nh_energy_slab(
    const float* slab, const float4* uu, const float* wq)
{
    float eu[4][3];
    eu[0][0]=uu[0].x; eu[0][1]=uu[0].y; eu[0][2]=uu[0].z;
    eu[1][0]=uu[1].x; eu[1][1]=uu[1].y; eu[1][2]=uu[1].z;
    eu[2][0]=uu[2].x; eu[2][1]=uu[2].y; eu[2][2]=uu[2].z;
    eu[3][0]=uu[3].x; eu[3][1]=uu[3].y; eu[3][2]=uu[3].z;

    float a = 0.f;
    #pragma unroll
    for (int q = 0; q < 4; ++q) {
        const float4 f0 = *reinterpret_cast<const float4*>(slab + q*12 + 0);
        const float4 f1 = *reinterpret_cast<const float4*>(slab + q*12 + 4);
        const float4 f2 = *reinterpret_cast<const float4*>(slab + q*12 + 8);
        const float d[12] = {f0.x,f0.y,f0.z,f0.w, f1.x,f1.y,f1.z,f1.w,
                             f2.x,f2.y,f2.z,f2.w};   // d[n*3 + j]
        float F[3][3];
        #pragma unroll
        for (int i = 0; i < 3; ++i) {
            #pragma unroll
            for (int j = 0; j < 3; ++j) {
                float g = 0.f;
                #pragma unroll
                for (int n = 0; n < 4; ++n)
                    g = fmaf(eu[n][i], d[n*3 + j], g);
                F[i][j] = g + ((i == j) ? 1.f : 0.f);
            }
        }
        const float J =
              F[0][0] * (F[1][1]*F[2][2] - F[1][2]*F[2][1])
            - F[0][1] * (F[1][0]*F[2][2] - F[1][2]*F[2][0])
            + F[0][2] * (F[1][0]*F[2][1] - F[1][1]*F[2][0]);
        float IC = 0.f;
        #pragma unroll
        for (int i = 0; i < 3; ++i)
            #pragma unroll
            for (int j = 0; j < 3; ++j)
                IC = fmaf(F[i][j], F[i][j], IC);
        const float lj = __logf(fmaxf(J, EPS_C));
        const float W = 0.5f * MU_C * (IC - 3.f)
                      + 0.25f * LM_C * fmaf(J, J, -1.f)
                      - LOGC * lj;
        a = fmaf(W, wq[q], a);
    }
    return a;
}

__global__ __launch_bounds__(256) void nh_partial_v15(
    const float4* __restrict__ ut,       // (n_nodes, 4) padded float4
    const ni4*    __restrict__ elp,      // (n_elem)
    const nf4*    __restrict__ dnp,      // (n_elem*12)
    const nf4*    __restrict__ djp,      // (n_elem)
    const float*  __restrict__ qw,       // (4,)
    float* __restrict__ partial,         // (gridDim.x, 4)
    int n_elem, int ntiles, int chunk)
{
    __shared__ float s_dn[2][ELB * SLAB];
    __shared__ int   s_el[2][ELB * 4];
    __shared__ float s_dj[2][ELB * 4];
    __shared__ float s_red[4][4];

    const int t = threadIdx.x;
    const int b = t & 3;
    const int p = t >> 2;

    const int t0  = blockIdx.x * chunk;
    const int cnt = min(chunk, ntiles - t0);

    float acc = 0.f;

    if (cnt > 0) {
        const float4 w4 = *reinterpret_cast<const float4*>(qw);
        const int dnmax = n_elem * 12 - 1;
        const int elmax = n_elem - 1;
        const int tlast = ntiles - 1;

        const int oA = (t       / 12) * SLAB + (t       % 12) * 4;
        const int oB = ((t+256) / 12) * SLAB + ((t+256) % 12) * 4;
        const int oC = ((t+512) / 12) * SLAB + ((t+512) % 12) * 4;

        float4 uuA[4], uuB[4];

        // prologue: stage tile t0 -> buf0, gather uuA
        {
            const int base = t0 * 768;
            const nf4 r0 = __builtin_nontemporal_load(dnp + min(base + t,       dnmax));
            const nf4 r1 = __builtin_nontemporal_load(dnp + min(base + t + 256, dnmax));
            const nf4 r2 = __builtin_nontemporal_load(dnp + min(base + t + 512, dnmax));
            ni4 rel; nf4 rdj;
            if (t < 64)       rel = __builtin_nontemporal_load(elp + min(t0*64 + t, elmax));
            else if (t < 128) rdj = __builtin_nontemporal_load(djp + min(t0*64 + (t-64), elmax));
            *reinterpret_cast<float4*>(&s_dn[0][oA]) = (const float4&)r0;
            *reinterpret_cast<float4*>(&s_dn[0][oB]) = (const float4&)r1;
            *reinterpret_cast<float4*>(&s_dn[0][oC]) = (const float4&)r2;
            if (t < 64)       reinterpret_cast<int4*>(s_el[0])[t] = (const int4&)rel;
            else if (t < 128) reinterpret_cast<float4*>(s_dj[0])[t-64] = (const float4&)rdj;
            __syncthreads();
            const int4 nd = reinterpret_cast<const int4*>(s_el[0])[p];
            uuA[0] = ut[(nd.x << 2) | b];
            uuA[1] = ut[(nd.y << 2) | b];
            uuA[2] = ut[(nd.z << 2) | b];
            uuA[3] = ut[(nd.w << 2) | b];
        }

        #define NH_BODY(M, CUR, UUC, UUN)                                             \
        {                                                                             \
            const int tn = min(t0 + (M) + 1, tlast);                                  \
            const int base = tn * 768;                                                \
            const nf4 r0 = __builtin_nontemporal_load(dnp + min(base + t,       dnmax)); \
            const nf4 r1 = __builtin_nontemporal_load(dnp + min(base + t + 256, dnmax)); \
            const nf4 r2 = __builtin_nontemporal_load(dnp + min(base + t + 512, dnmax)); \
            ni4 rel; nf4 rdj;                                                         \
            if (t < 64)       rel = __builtin_nontemporal_load(elp + min(tn*64 + t, elmax)); \
            else if (t < 128) rdj = __builtin_nontemporal_load(djp + min(tn*64 + (t-64), elmax)); \
            {                                                                         \
                const int e = (t0 + (M)) * 64 + p;                                    \
                const float sc = ((M) < cnt && e < n_elem) ? 1.f : 0.f;               \
                const float* dj4 = &s_dj[CUR][p * 4];                                 \
                const float wq[4] = {dj4[0]*w4.x*sc, dj4[1]*w4.y*sc,                  \
                                     dj4[2]*w4.z*sc, dj4[3]*w4.w*sc};                 \
                acc += nh_energy_slab(&s_dn[CUR][p * SLAB], UUC, wq);                 \
            }                                                                         \
            __syncthreads();                                                          \
            *reinterpret_cast<float4*>(&s_dn[(CUR)^1][oA]) = (const float4&)r0;       \
            *reinterpret_cast<float4*>(&s_dn[(CUR)^1][oB]) = (const float4&)r1;       \
            *reinterpret_cast<float4*>(&s_dn[(CUR)^1][oC]) = (const float4&)r2;       \
            if (t < 64)       reinterpret_cast<int4*>(s_el[(CUR)^1])[t] = (const int4&)rel; \
            else if (t < 128) reinterpret_cast<float4*>(s_dj[(CUR)^1])[t-64] = (const float4&)rdj; \
            __syncthreads();                                                          \
            {                                                                         \
                const int4 nd = reinterpret_cast<const int4*>(s_el[(CUR)^1])[p];      \
                UUN[0] = ut[(nd.x << 2) | b];                                         \
                UUN[1] = ut[(nd.y << 2) | b];                                         \
                UUN[2] = ut[(nd.z << 2) | b];                                         \
                UUN[3] = ut[(nd.w << 2) | b];                                         \
            }                                                                         \
        }

        const int iters = (cnt + 1) & ~1;   // even, block-uniform
        for (int m = 0; m < iters; m += 2) {
            NH_BODY(m,     0, uuA, uuB)
            NH_BODY(m + 1, 1, uuB, uuA)
        }
        #undef NH_BODY
    }

    #pragma unroll
    for (int off = 32; off >= 4; off >>= 1)
        acc += __shfl_down(acc, off);

    const int lane = t & 63;
    const int wid  = t >> 6;
    if (lane < 4) s_red[wid][lane] = acc;
    __syncthreads();
    if (t < 4)
        partial[(size_t)blockIdx.x * 4 + t] =
            (s_red[0][t] + s_red[1][t]) + (s_red[2][t] + s_red[3][t]);
}

__global__ __launch_bounds__(256) void nh_final(
    const float* __restrict__ partial, float* __restrict__ out, int nparts)
{
    float accb[4] = {0.f, 0.f, 0.f, 0.f};
    for (int i = threadIdx.x; i < nparts; i += 256) {
        const float4 p = reinterpret_cast<const float4*>(partial)[i];
        accb[0] += p.x; accb[1] += p.y; accb[2] += p.z; accb[3] += p.w;
    }
    #pragma unroll
    for (int b = 0; b < 4; ++b) {
        float v = accb[b];
        #pragma unroll
        for (int off = 32; off > 0; off >>= 1)
            v += __shfl_down(v, off);
        accb[b] = v;
    }
    __shared__ float lds[4][4];
    const int lane = threadIdx.x & 63;
    const int wid  = threadIdx.x >> 6;
    if (lane == 0) {
        #pragma unroll
        for (int b = 0; b < 4; ++b) lds[wid][b] = accb[b];
    }
    __syncthreads();
    if (threadIdx.x == 0) {
        #pragma unroll
        for (int b = 0; b < 4; ++b)
            out[b] = (lds[0][b] + lds[1][b]) + (lds[2][b] + lds[3][b]);
    }
}

extern "C" void kernel_launch(void* const* d_in, const int* in_sizes, int n_in,
                              void* d_out, int out_size, void* d_ws, size_t ws_size,
                              hipStream_t stream) {
    const float* u        = (const float*)d_in[0];
    const int*   elements = (const int*)d_in[1];
    const float* dN_dx    = (const float*)d_in[2];
    const float* detJ     = (const float*)d_in[3];
    const float* qw       = (const float*)d_in[4];
    float* out = (float*)d_out;

    const int B       = out_size;            // 4
    const int n_nodes = in_sizes[0] / (3 * B);
    const int n_elem  = in_sizes[1] / 4;

    const int threads = 256;
    const int ntiles  = (n_elem + ELB - 1) / ELB;
    const int nblocks = (ntiles < NBLK) ? ntiles : NBLK;
    const int chunk   = (ntiles + nblocks - 1) / nblocks;

    const size_t ut_bytes = (size_t)n_nodes * 4 * sizeof(float4);
    float4* ut      = (float4*)d_ws;
    float*  partial = (float*)((char*)d_ws + ut_bytes);

    const int tb = (n_nodes + threads - 1) / threads;
    nh_transpose_u_pad<<<tb, threads, 0, stream>>>(u, ut, n_nodes);

    nh_partial_v15<<<nblocks, threads, 0, stream>>>(
        ut, reinterpret_cast<const ni4*>(elements),
        reinterpret_cast<const nf4*>(dN_dx),
        reinterpret_cast<const nf4*>(detJ),
        qw, partial, n_elem, ntiles, chunk);

    nh_final<<<1, threads, 0, stream>>>(partial, out, nblocks);
}